// Round 5
// baseline (463.861 us; speedup 1.0000x reference)
//
#include <hip/hip_runtime.h>
#include <hip/hip_bf16.h>

typedef __attribute__((ext_vector_type(8))) short bf16x8;
typedef __attribute__((ext_vector_type(4))) float f32x4;

#define BB   64
#define LL   512
#define CIN  64
#define FF   128
#define KW   7
#define OUTL 506
#define KC   448        // KW*CIN  (conv GEMM K)
#define KL   896        // KW*FF   (local GEMM K)
#define BK   32         // LDS K-chunk (both GEMMs)
#define NCHC 14         // KC / BK  (conv)
#define NCHL 28         // KL / BK  (local)
#define EPSV 1e-3f

#define CONVB ((BB * LL) / 64)       // 512 conv blocks

static __device__ __forceinline__ short f2bf(float f) {
    // fp32 -> bf16, round-to-nearest-even
    unsigned u = __builtin_bit_cast(unsigned, f);
    unsigned r = (u + 0x7fffu + ((u >> 16) & 1u)) >> 16;
    return (short)r;
}

// async global->LDS, 16 B per lane; LDS dest = wave-uniform base + lane*16
static __device__ __forceinline__ void g2lds16(const float* g, float* l) {
    __builtin_amdgcn_global_load_lds(
        (const __attribute__((address_space(1))) unsigned int*)g,
        (__attribute__((address_space(3))) unsigned int*)l, 16, 0, 0);
}

// ---------------------------------------------------------------- kernel 1
// conv-as-GEMM, prep folded in (identical to round 4).
__global__ __launch_bounds__(256) void conv_bn_kernel(
    const float* __restrict__ x, const float* __restrict__ cw,
    const float* __restrict__ cb, const float* __restrict__ g,
    const float* __restrict__ be, const float* __restrict__ mu,
    const float* __restrict__ va, short* __restrict__ y) {
    __shared__ float wchunk[2][BK * FF];       // 2 x 16 KB
    const int lane = threadIdx.x & 63;
    const int wid  = threadIdx.x >> 6;
    const int m0   = blockIdx.x * 64;
    const int nb   = wid * 32;
    const int q    = lane >> 4;
    const int ln   = lane & 15;

    const float* xbase[4];
    int lrow[4];
#pragma unroll
    for (int mt = 0; mt < 4; ++mt) {
        int m = m0 + mt * 16 + ln;
        int b = m >> 9, l = m & 511;                    // m = b*512 + l
        lrow[mt]  = l;
        xbase[mt] = x + (long)((b << 9) + l - 3) * CIN; // only deref'd when valid
    }

    f32x4 acc[4][2];
#pragma unroll
    for (int mt = 0; mt < 4; ++mt)
#pragma unroll
        for (int nt = 0; nt < 2; ++nt) acc[mt][nt] = (f32x4){0.f, 0.f, 0.f, 0.f};

#define STAGEW(kc_, buf_)                                                      \
    {                                                                          \
        _Pragma("unroll")                                                      \
        for (int r = 0; r < 4; ++r) {                                          \
            const int ib = (r * 4 + wid) * 256;                                \
            g2lds16(cw + (size_t)(kc_) * FF + ib + lane * 4, &(buf_)[ib]);     \
        }                                                                      \
    }

    STAGEW(0, wchunk[0]);

    for (int c = 0; c < NCHC; ++c) {
        __syncthreads();                       // drains vmcnt -> chunk c resident
        if (c + 1 < NCHC) STAGEW((c + 1) * BK, wchunk[(c + 1) & 1]);
        const float* wb = wchunk[c & 1];

        const int ko = c * BK + q * 8;
        const int kw = ko >> 6;                // uniform over the 8-frag (8|ko)

        bf16x8 a[4];
#pragma unroll
        for (int mt = 0; mt < 4; ++mt) {
            const bool v = (unsigned)(lrow[mt] - 3 + kw) < (unsigned)LL;
            f32x4 lo = v ? *(const f32x4*)(xbase[mt] + ko)     : (f32x4){0.f, 0.f, 0.f, 0.f};
            f32x4 hi = v ? *(const f32x4*)(xbase[mt] + ko + 4) : (f32x4){0.f, 0.f, 0.f, 0.f};
#pragma unroll
            for (int j = 0; j < 4; ++j) {
                a[mt][j]     = f2bf(lo[j]);
                a[mt][j + 4] = f2bf(hi[j]);
            }
        }

        bf16x8 bf[2];
#pragma unroll
        for (int nt = 0; nt < 2; ++nt) {
            const int n = nb + nt * 16 + ln;
#pragma unroll
            for (int j = 0; j < 8; ++j)
                bf[nt][j] = f2bf(wb[(q * 8 + j) * FF + n]);
        }
#pragma unroll
        for (int mt = 0; mt < 4; ++mt)
#pragma unroll
            for (int nt = 0; nt < 2; ++nt)
                acc[mt][nt] = __builtin_amdgcn_mfma_f32_16x16x32_bf16(
                    a[mt], bf[nt], acc[mt][nt], 0, 0, 0);
    }
#undef STAGEW

#pragma unroll
    for (int nt = 0; nt < 2; ++nt) {
        const int n = nb + nt * 16 + ln;
        const float s  = g[n] * rsqrtf(va[n] + EPSV);
        const float b2 = s * (cb[n] - mu[n]) + be[n];
#pragma unroll
        for (int mt = 0; mt < 4; ++mt) {
            const int mbase = m0 + mt * 16 + q * 4;
#pragma unroll
            for (int r = 0; r < 4; ++r) {
                float v = fmaxf(acc[mt][nt][r] * s + b2, 0.0f);
                y[(size_t)(mbase + r) * FF + n] = f2bf(v);
            }
        }
    }
}

// ---------------------------------------------------------------- kernel 2
// locally-connected (identical to round 4 / round 0 — best measured).
__global__ __launch_bounds__(256) void local_bn_kernel(
    const short* __restrict__ y, const float* __restrict__ lw,
    const float* __restrict__ lb, const float* __restrict__ g,
    const float* __restrict__ be, const float* __restrict__ mu,
    const float* __restrict__ va, float* __restrict__ out) {
    __shared__ float wtile[2][BK * FF];        // 2 x 16 KB
    const int l    = blockIdx.x;
    const int lane = threadIdx.x & 63;
    const int wid  = threadIdx.x >> 6;
    const int nb   = wid * 32;
    const int q    = lane >> 4;
    const int ln   = lane & 15;

    const float* wl = lw + (size_t)l * (KL * FF);

    const short* arow[4];
#pragma unroll
    for (int mt = 0; mt < 4; ++mt)
        arow[mt] = y + (size_t)(mt * 16 + ln) * (LL * FF) + (size_t)l * FF;

    f32x4 acc[4][2];
#pragma unroll
    for (int mt = 0; mt < 4; ++mt)
#pragma unroll
        for (int nt = 0; nt < 2; ++nt) acc[mt][nt] = (f32x4){0.f, 0.f, 0.f, 0.f};

    // stage chunk 0
    {
        const float* src = wl;
#pragma unroll
        for (int r = 0; r < 4; ++r)
            g2lds16(src + (size_t)(r * 256 + wid * 64 + lane) * 4,
                    &wtile[0][(r * 256 + wid * 64) * 4]);
    }

    for (int c = 0; c < NCHL; ++c) {
        __syncthreads();                       // drains vmcnt -> chunk c resident
        if (c + 1 < NCHL) {                    // prefetch chunk c+1 into other buf
            const float* src = wl + (size_t)(c + 1) * (BK * FF);
            float* dst = wtile[(c + 1) & 1];
#pragma unroll
            for (int r = 0; r < 4; ++r)
                g2lds16(src + (size_t)(r * 256 + wid * 64 + lane) * 4,
                        &dst[(r * 256 + wid * 64) * 4]);
        }
        const float* wb = wtile[c & 1];
        const int ko = c * BK + q * 8;

        bf16x8 a[4];
#pragma unroll
        for (int mt = 0; mt < 4; ++mt) a[mt] = *(const bf16x8*)(arow[mt] + ko);

        bf16x8 bf[2];
#pragma unroll
        for (int nt = 0; nt < 2; ++nt) {
            const int n = nb + nt * 16 + ln;
#pragma unroll
            for (int j = 0; j < 8; ++j)
                bf[nt][j] = f2bf(wb[(q * 8 + j) * FF + n]);
        }
#pragma unroll
        for (int mt = 0; mt < 4; ++mt)
#pragma unroll
            for (int nt = 0; nt < 2; ++nt)
                acc[mt][nt] = __builtin_amdgcn_mfma_f32_16x16x32_bf16(
                    a[mt], bf[nt], acc[mt][nt], 0, 0, 0);
    }

    // epilogue: + local_b[l], BN2, ReLU, fp32 store
#pragma unroll
    for (int nt = 0; nt < 2; ++nt) {
        const int n = nb + nt * 16 + ln;
        const float s  = g[n] * rsqrtf(va[n] + EPSV);
        const float b2 = s * (lb[(size_t)l * FF + n] - mu[n]) + be[n];
#pragma unroll
        for (int mt = 0; mt < 4; ++mt) {
            const int bbase = mt * 16 + q * 4;
#pragma unroll
            for (int r = 0; r < 4; ++r) {
                float v = fmaxf(acc[mt][nt][r] * s + b2, 0.0f);
                out[(size_t)(bbase + r) * (OUTL * FF) + (size_t)l * FF + n] = v;
            }
        }
    }
}

// ---------------------------------------------------------------- launch
// PROBE ROUND: local_bn_kernel launched 3x (idempotent). dur_us delta vs
// round 4 (380.6) reads off 2x the warm local-kernel duration:
//   dur <= ~425  -> local is near its stream floor; residual is conv/launch
//   425..470     -> local has 25-45 us cache-independent cost (LDS/VALU path)
//   > ~470       -> local dominates; restructure
extern "C" void kernel_launch(void* const* d_in, const int* in_sizes, int n_in,
                              void* d_out, int out_size, void* d_ws, size_t ws_size,
                              hipStream_t stream) {
    const float* x       = (const float*)d_in[0];
    const float* conv_w  = (const float*)d_in[1];
    const float* conv_b  = (const float*)d_in[2];
    const float* bn1_g   = (const float*)d_in[3];
    const float* bn1_b   = (const float*)d_in[4];
    const float* bn1_m   = (const float*)d_in[5];
    const float* bn1_v   = (const float*)d_in[6];
    const float* local_w = (const float*)d_in[7];
    const float* local_b = (const float*)d_in[8];
    const float* bn2_g   = (const float*)d_in[9];
    const float* bn2_b   = (const float*)d_in[10];
    const float* bn2_m   = (const float*)d_in[11];
    const float* bn2_v   = (const float*)d_in[12];
    float* out = (float*)d_out;

    short* ybf = (short*)d_ws;                   // (64, 512, 128) bf16

    conv_bn_kernel<<<CONVB, 256, 0, stream>>>(
        x, conv_w, conv_b, bn1_g, bn1_b, bn1_m, bn1_v, ybf);
    local_bn_kernel<<<OUTL, 256, 0, stream>>>(
        ybf, local_w, local_b, bn2_g, bn2_b, bn2_m, bn2_v, out);
    local_bn_kernel<<<OUTL, 256, 0, stream>>>(
        ybf, local_w, local_b, bn2_g, bn2_b, bn2_m, bn2_v, out);
    local_bn_kernel<<<OUTL, 256, 0, stream>>>(
        ybf, local_w, local_b, bn2_g, bn2_b, bn2_m, bn2_v, out);
}